// Round 9
// baseline (75.511 us; speedup 1.0000x reference)
//
#include <hip/hip_runtime.h>
#include <stdint.h>

#define BB 2
#define DD 64
#define HH 128
#define WW 128
#define NVOX (DD*HH*WW)        // 2^20 per batch
#define TOTAL (BB*NVOX)        // 2097152
#define INF16 65535
#define HBINS 36868            // > max finite dsq (36227)
#define LBINS 512
#define NSMALL 7
#define NWORDS (TOTAL/16)      // 131072 uint16 mask words per volume
#define ZEROINTS (4*HBINS + 4*NSMALL*LBINS + 8)   // bigh||smallh||maxv||done
#define TPITCH 130   // ushort pitch for xy tile
#define ZPITCH 68    // ushort pitch for z tile

__device__ __forceinline__ int aload(const int* p)
{
    return __hip_atomic_load(p, __ATOMIC_RELAXED, __HIP_MEMORY_SCOPE_AGENT);
}

// ---------- nearest set bit at position >= x in 128-bit mask (hi:lo) -------
__device__ __forceinline__ int dist128(uint64_t lo, uint64_t hi, int x)
{
    uint64_t a, b;
    if (x == 0)      { a = lo; b = hi; }
    else if (x < 64) { a = (lo >> x) | (hi << (64 - x)); b = hi >> x; }
    else             { a = hi >> (x - 64); b = 0; }
    if (a) return __builtin_ctzll(a);
    if (b) return 64 + __builtin_ctzll(b);
    return 999;
}

// ---------- bitpack: float>0.5 masks -> 16-voxel uint16 words; zero ints ---
__global__ __launch_bounds__(256)
void bitpack_kernel(const float* __restrict__ pred, const float* __restrict__ targ,
                    uint16_t* __restrict__ pb, uint16_t* __restrict__ tb,
                    int* __restrict__ zint)
{
    int gt = blockIdx.x * 256 + threadIdx.x;       // 0..NWORDS-1
    for (int t = gt; t < ZEROINTS; t += NWORDS) zint[t] = 0;

    const float4* p4 = (const float4*)pred + gt * 4;
    const float4* t4 = (const float4*)targ + gt * 4;
    uint32_t pbits = 0, tbits = 0;
    #pragma unroll
    for (int j = 0; j < 4; ++j) {
        float4 v = p4[j];
        pbits |= ((uint32_t)(v.x > 0.5f) | (uint32_t)(v.y > 0.5f) << 1 |
                  (uint32_t)(v.z > 0.5f) << 2 | (uint32_t)(v.w > 0.5f) << 3) << (4 * j);
        float4 w = t4[j];
        tbits |= ((uint32_t)(w.x > 0.5f) | (uint32_t)(w.y > 0.5f) << 1 |
                  (uint32_t)(w.z > 0.5f) << 2 | (uint32_t)(w.w > 0.5f) << 3) << (4 * j);
    }
    pb[gt] = (uint16_t)pbits;
    tb[gt] = (uint16_t)tbits;
}

// ---------- edges (bit-ops) + x-EDT (bitmask) + y-EDT (LDS) ----------------
__global__ __launch_bounds__(1024)
void edt_xy_kernel(const uint16_t* __restrict__ pb, const uint16_t* __restrict__ tb,
                   uint16_t* __restrict__ epb, uint16_t* __restrict__ egb,
                   uint16_t* __restrict__ d0, uint16_t* __restrict__ d1)
{
    __shared__ uint16_t w16[1024];
    __shared__ uint16_t t16[HH * TPITCH];
    int gid = blockIdx.x, tid = threadIdx.x;
    int dir = gid & 1;
    int bz  = gid >> 1;                 // b*DD + z
    int z   = bz & (DD - 1);
    const uint16_t* src = dir ? pb : tb;
    uint16_t* eout      = dir ? epb : egb;
    uint16_t* dout      = dir ? d1 : d0;
    int wbase = bz * 1024;
    size_t sbase = (size_t)bz * (HH * WW);

    int row = tid >> 3;                 // y
    int seg = tid & 7;
    int x0 = seg * 16;

    uint32_t m  = src[wbase + tid];
    uint32_t zm = (z > 0)      ? src[wbase + tid - 1024] : 0;
    uint32_t zp = (z < DD - 1) ? src[wbase + tid + 1024] : 0;
    w16[tid] = (uint16_t)m;
    __syncthreads();
    uint32_t ym = (row > 0)      ? w16[tid - 8] : 0;
    uint32_t yp = (row < HH - 1) ? w16[tid + 8] : 0;
    uint32_t lw = (seg > 0)      ? w16[tid - 1] : 0;
    uint32_t nw = (seg < 7)      ? w16[tid + 1] : 0;
    uint32_t L = ((m << 1) | (lw >> 15)) & 0xFFFFu;
    uint32_t R = ((m >> 1) | ((nw & 1u) << 15)) & 0xFFFFu;
    uint32_t er = m & L & R & ym & yp & zm & zp;
    uint32_t eb = m & ~er;              // edge bits
    eout[wbase + tid] = (uint16_t)eb;

    // --- x-EDT via 128-bit row bitmask of edge bits ------------------------
    int lanebase = (tid & 63) & ~7;
    uint64_t lo = 0, hi = 0;
    #pragma unroll
    for (int j = 0; j < 4; ++j) {
        lo |= ((uint64_t)((uint32_t)__shfl((int)eb, lanebase + j, 64) & 0xFFFFu)) << (16 * j);
        hi |= ((uint64_t)((uint32_t)__shfl((int)eb, lanebase + 4 + j, 64) & 0xFFFFu)) << (16 * j);
    }
    uint64_t rlo = __brevll(hi), rhi = __brevll(lo);

    #pragma unroll
    for (int j = 0; j < 16; ++j) {
        int x = x0 + j;
        int dr = dist128(lo, hi, x);
        int dl = dist128(rlo, rhi, 127 - x);
        int dist = min(dr, dl);
        int dsq = (dist > 127) ? INF16 : dist * dist;
        t16[row * TPITCH + x] = (uint16_t)dsq;
    }
    __syncthreads();

    // --- y-EDT (early-exit), write d ---------------------------------------
    int xx = tid & 127;
    int yg = tid >> 7;                  // 0..7
    for (int k = 0; k < 16; ++k) {
        int y = yg + k * 8;
        int best = t16[y * TPITCH + xx];
        for (int o = 1; o < HH && o * o < best; ++o) {
            int osq = o * o;
            int ylo = y - o, yhi = y + o;
            if (ylo >= 0) best = min(best, (int)t16[ylo * TPITCH + xx] + osq);
            if (yhi < HH) best = min(best, (int)t16[yhi * TPITCH + xx] + osq);
        }
        dout[sbase + (size_t)y * WW + xx] = (uint16_t)best;
    }
}

// ---------- z EDT + histogram + (last block) fold + percentile -------------
__global__ __launch_bounds__(1024)
void edt_z_hist_kernel(const uint16_t* __restrict__ d0,
                       const uint16_t* __restrict__ d1,
                       const uint16_t* __restrict__ epb,
                       const uint16_t* __restrict__ egb,
                       int* __restrict__ bigh,
                       int* __restrict__ smallh,
                       int* __restrict__ maxv,
                       int* __restrict__ done,
                       float* __restrict__ out)
{
    __shared__ uint16_t tile[DD * ZPITCH];
    __shared__ int lh[LBINS];
    __shared__ int blkmax, lastflag;
    int tid = threadIdx.x;           // 1024
    if (tid < LBINS) lh[tid] = 0;
    if (tid == 0) blkmax = 0;

    int blk = blockIdx.x;            // dir | xt<<1 | y<<2 | b<<9
    int dir = blk & 1;
    int xt  = (blk >> 1) & 1;
    int y   = (blk >> 2) & 127;
    int b   = blk >> 9;
    const uint16_t* d = dir ? d1 : d0;
    const uint16_t* evalbits = dir ? egb : epb;  // dir0: histogram at pred edges
    size_t base = (size_t)b * NVOX + (size_t)y * WW + xt * 64;

    {   // cooperative tile load: 64 z-rows x 128B
        int z = tid >> 4, sg = tid & 15;
        uint2 v = *(const uint2*)(d + base + (size_t)z * (HH * WW) + sg * 4);
        *(uint2*)&tile[z * ZPITCH + sg * 4] = v;
    }
    __syncthreads();

    int xx = tid & 63;
    int zg = tid >> 6;               // 0..15
    int x  = xt * 64 + xx;
    int g = b * 2 + dir;
    int* gbig = bigh + (size_t)g * HBINS;
    int lane = tid & 63;

    #pragma unroll
    for (int k = 0; k < 4; ++k) {
        int z = zg + k * 16;
        int best = tile[z * ZPITCH + xx];
        for (int o = 1; o < DD && o * o < best; ++o) {
            int osq = o * o;
            int zlo = z - o, zhi = z + o;
            if (zlo >= 0) best = min(best, (int)tile[zlo * ZPITCH + xx] + osq);
            if (zhi < DD) best = min(best, (int)tile[zhi * ZPITCH + xx] + osq);
        }
        int v = best; if (v >= HBINS) v = HBINS - 1;
        uint32_t ew = evalbits[((b * DD + z) * HH + y) * 8 + (x >> 4)];
        bool valid = (ew >> (x & 15)) & 1;
        // wave max of valid v -> block max (for percentile early stop)
        int vm = valid ? v : 0;
        #pragma unroll
        for (int o = 1; o < 64; o <<= 1) vm = max(vm, __shfl_xor(vm, o, 64));
        if (lane == 0 && vm > 0) atomicMax(&blkmax, vm);
        unsigned long long active = __ballot(valid);
        while (active) {
            int leader = __ffsll(active) - 1;
            int lv = __shfl(v, leader, 64);
            unsigned long long same = __ballot(valid && (v == lv));
            if (lane == leader) {
                int cnt = __popcll(same);
                if (lv < LBINS) atomicAdd(&lh[lv], cnt);
                else            atomicAdd(&gbig[lv], cnt);
            }
            active &= ~same;
        }
    }
    __syncthreads();
    int slot = (blk >> 1) & 7;       // spread flush over 8 targets per g
    int* dst = (slot == 0) ? gbig : (smallh + ((size_t)g * NSMALL + (slot - 1)) * LBINS);
    if (tid < LBINS) {
        int c = lh[tid];
        if (c) atomicAdd(&dst[tid], c);
    }
    __syncthreads();                 // all flush atomics issued+drained (waitcnt before barrier)
    if (tid == 0) {
        atomicMax(&maxv[g], blkmax);
        __threadfence();
        int old = __hip_atomic_fetch_add(done, 1, __ATOMIC_ACQ_REL, __HIP_MEMORY_SCOPE_AGENT);
        lastflag = (old == (int)gridDim.x - 1);
    }
    __syncthreads();
    if (!lastflag) return;

    // ---------------- last block only: fold + percentile ------------------
    int wid = tid >> 6;
    if (wid < 4) {
        int gg = wid;
        const int* gbig2 = bigh + (size_t)gg * HBINS;
        const int* gsm2  = smallh + (size_t)gg * NSMALL * LBINS;
        int mb = aload(&maxv[gg]);
        if (mb >= HBINS) mb = HBINS - 1;

        // pass 1: total count n
        int n = 0;
        for (int c0 = 0; c0 <= mb; c0 += 64) {
            int bin = c0 + lane;
            int cnt = 0;
            if (bin <= mb) {
                cnt = aload(&gbig2[bin]);
                if (bin < LBINS) {
                    #pragma unroll
                    for (int s = 0; s < NSMALL; ++s) cnt += aload(&gsm2[s * LBINS + bin]);
                }
            }
            #pragma unroll
            for (int o = 1; o < 64; o <<= 1) cnt += __shfl_xor(cnt, o, 64);
            n += cnt;
        }

        float pos = 0.95f * (float)(n - 1);
        float fpos = floorf(pos);
        int lo = (int)fpos;
        int nm1 = n - 1; if (nm1 < 0) nm1 = 0;
        if (lo < 0) lo = 0;
        if (lo > nm1) lo = nm1;
        int hi = lo + 1; if (hi > nm1) hi = nm1;
        float frac = pos - fpos;

        // pass 2: rank select
        int basec = 0, sel0 = 0, sel1 = 0;
        bool f0 = false, f1 = false;
        for (int c0 = 0; c0 <= mb && !(f0 && f1); c0 += 64) {
            int bin = c0 + lane;
            int cnt = 0;
            if (bin <= mb) {
                cnt = aload(&gbig2[bin]);
                if (bin < LBINS) {
                    #pragma unroll
                    for (int s = 0; s < NSMALL; ++s) cnt += aload(&gsm2[s * LBINS + bin]);
                }
            }
            int inc = cnt;
            #pragma unroll
            for (int o = 1; o < 64; o <<= 1) {
                int t = __shfl_up(inc, o, 64);
                if (lane >= o) inc += t;
            }
            int exc = inc - cnt;
            unsigned long long b0 = __ballot(!f0 && lo >= basec + exc && lo < basec + inc);
            if (b0) { sel0 = c0 + (__ffsll(b0) - 1); f0 = true; }
            unsigned long long b1 = __ballot(!f1 && hi >= basec + exc && hi < basec + inc);
            if (b1) { sel1 = c0 + (__ffsll(b1) - 1); f1 = true; }
            basec += __shfl(inc, 63, 64);
        }
        if (lane == 0) {
            float a = sqrtf((float)sel0);
            float bv = sqrtf((float)sel1);
            float val = a + frac * (bv - a);
            atomicMax((int*)out + (gg >> 1), __float_as_int(val));  // val>=0
        }
    }
}

extern "C" void kernel_launch(void* const* d_in, const int* in_sizes, int n_in,
                              void* d_out, int out_size, void* d_ws, size_t ws_size,
                              hipStream_t stream)
{
    const float* pred = (const float*)d_in[0];
    const float* targ = (const float*)d_in[1];
    float* out = (float*)d_out;

    uint8_t* ws = (uint8_t*)d_ws;
    uint16_t* pb  = (uint16_t*)ws;                   // NWORDS u16
    uint16_t* tb  = pb + NWORDS;                     // NWORDS u16
    uint16_t* epb = tb + NWORDS;                     // NWORDS u16
    uint16_t* egb = epb + NWORDS;                    // NWORDS u16
    uint16_t* d0  = egb + NWORDS;                    // TOTAL u16
    uint16_t* d1  = d0 + TOTAL;                      // TOTAL u16
    int* bigh     = (int*)(d1 + TOTAL);              // 4*HBINS ints
    int* smallh   = bigh + 4 * HBINS;                // 4*NSMALL*LBINS ints
    int* maxv     = smallh + 4 * NSMALL * LBINS;     // 4 ints
    int* done     = maxv + 4;                        // 1 int
    // bitpack zeroes [bigh .. bigh+ZEROINTS) = bigh||smallh||maxv||done

    bitpack_kernel<<<NWORDS/256, 256, 0, stream>>>(pred, targ, pb, tb, bigh);
    edt_xy_kernel<<<BB*DD*2, 1024, 0, stream>>>(pb, tb, epb, egb, d0, d1);
    edt_z_hist_kernel<<<BB*HH*2*2, 1024, 0, stream>>>(d0, d1, epb, egb,
                                                      bigh, smallh, maxv, done, out);
}

// Round 10
// 47.517 us; speedup vs baseline: 1.5891x; 1.5891x over previous
//
#include <hip/hip_runtime.h>
#include <stdint.h>

#define BB 2
#define DD 64
#define HH 128
#define WW 128
#define NVOX (DD*HH*WW)        // 2^20 per batch
#define TOTAL (BB*NVOX)        // 2097152
#define INF16 65535
#define HBINS 36868            // > max finite dsq (36227)
#define LBINS 512
#define NSMALL 7
#define NWORDS (TOTAL/16)      // 131072 uint16 mask words per volume
#define ZEROINTS (4*HBINS + 4*NSMALL*LBINS + 4)   // bigh||smallh||maxv
#define TPITCH 130   // ushort pitch for xy tile
#define ZPITCH 68    // ushort pitch for z tile

__device__ __forceinline__ int aload(const int* p)
{
    return __hip_atomic_load(p, __ATOMIC_RELAXED, __HIP_MEMORY_SCOPE_AGENT);
}

// ---------- nearest set bit at position >= x in 128-bit mask (hi:lo) -------
__device__ __forceinline__ int dist128(uint64_t lo, uint64_t hi, int x)
{
    uint64_t a, b;
    if (x == 0)      { a = lo; b = hi; }
    else if (x < 64) { a = (lo >> x) | (hi << (64 - x)); b = hi >> x; }
    else             { a = hi >> (x - 64); b = 0; }
    if (a) return __builtin_ctzll(a);
    if (b) return 64 + __builtin_ctzll(b);
    return 999;
}

// ---------- bitpack: float>0.5 masks -> 16-voxel uint16 words; zero ints ---
__global__ __launch_bounds__(256)
void bitpack_kernel(const float* __restrict__ pred, const float* __restrict__ targ,
                    uint16_t* __restrict__ pb, uint16_t* __restrict__ tb,
                    int* __restrict__ zint)
{
    int gt = blockIdx.x * 256 + threadIdx.x;       // 0..NWORDS-1
    for (int t = gt; t < ZEROINTS; t += NWORDS) zint[t] = 0;

    const float4* p4 = (const float4*)pred + gt * 4;
    const float4* t4 = (const float4*)targ + gt * 4;
    uint32_t pbits = 0, tbits = 0;
    #pragma unroll
    for (int j = 0; j < 4; ++j) {
        float4 v = p4[j];
        pbits |= ((uint32_t)(v.x > 0.5f) | (uint32_t)(v.y > 0.5f) << 1 |
                  (uint32_t)(v.z > 0.5f) << 2 | (uint32_t)(v.w > 0.5f) << 3) << (4 * j);
        float4 w = t4[j];
        tbits |= ((uint32_t)(w.x > 0.5f) | (uint32_t)(w.y > 0.5f) << 1 |
                  (uint32_t)(w.z > 0.5f) << 2 | (uint32_t)(w.w > 0.5f) << 3) << (4 * j);
    }
    pb[gt] = (uint16_t)pbits;
    tb[gt] = (uint16_t)tbits;
}

// ---------- edges (bit-ops) + x-EDT (bitmask) + y-EDT (LDS) ----------------
__global__ __launch_bounds__(1024)
void edt_xy_kernel(const uint16_t* __restrict__ pb, const uint16_t* __restrict__ tb,
                   uint16_t* __restrict__ epb, uint16_t* __restrict__ egb,
                   uint16_t* __restrict__ d0, uint16_t* __restrict__ d1)
{
    __shared__ uint16_t w16[1024];
    __shared__ uint16_t t16[HH * TPITCH];
    int gid = blockIdx.x, tid = threadIdx.x;
    int dir = gid & 1;
    int bz  = gid >> 1;                 // b*DD + z
    int z   = bz & (DD - 1);
    const uint16_t* src = dir ? pb : tb;
    uint16_t* eout      = dir ? epb : egb;
    uint16_t* dout      = dir ? d1 : d0;
    int wbase = bz * 1024;
    size_t sbase = (size_t)bz * (HH * WW);

    int row = tid >> 3;                 // y
    int seg = tid & 7;
    int x0 = seg * 16;

    uint32_t m  = src[wbase + tid];
    uint32_t zm = (z > 0)      ? src[wbase + tid - 1024] : 0;
    uint32_t zp = (z < DD - 1) ? src[wbase + tid + 1024] : 0;
    w16[tid] = (uint16_t)m;
    __syncthreads();
    uint32_t ym = (row > 0)      ? w16[tid - 8] : 0;
    uint32_t yp = (row < HH - 1) ? w16[tid + 8] : 0;
    uint32_t lw = (seg > 0)      ? w16[tid - 1] : 0;
    uint32_t nw = (seg < 7)      ? w16[tid + 1] : 0;
    uint32_t L = ((m << 1) | (lw >> 15)) & 0xFFFFu;
    uint32_t R = ((m >> 1) | ((nw & 1u) << 15)) & 0xFFFFu;
    uint32_t er = m & L & R & ym & yp & zm & zp;
    uint32_t eb = m & ~er;              // edge bits
    eout[wbase + tid] = (uint16_t)eb;

    // --- x-EDT via 128-bit row bitmask of edge bits ------------------------
    int lanebase = (tid & 63) & ~7;
    uint64_t lo = 0, hi = 0;
    #pragma unroll
    for (int j = 0; j < 4; ++j) {
        lo |= ((uint64_t)((uint32_t)__shfl((int)eb, lanebase + j, 64) & 0xFFFFu)) << (16 * j);
        hi |= ((uint64_t)((uint32_t)__shfl((int)eb, lanebase + 4 + j, 64) & 0xFFFFu)) << (16 * j);
    }
    uint64_t rlo = __brevll(hi), rhi = __brevll(lo);

    #pragma unroll
    for (int j = 0; j < 16; ++j) {
        int x = x0 + j;
        int dr = dist128(lo, hi, x);
        int dl = dist128(rlo, rhi, 127 - x);
        int dist = min(dr, dl);
        int dsq = (dist > 127) ? INF16 : dist * dist;
        t16[row * TPITCH + x] = (uint16_t)dsq;
    }
    __syncthreads();

    // --- y-EDT (early-exit), write d ---------------------------------------
    int xx = tid & 127;
    int yg = tid >> 7;                  // 0..7
    for (int k = 0; k < 16; ++k) {
        int y = yg + k * 8;
        int best = t16[y * TPITCH + xx];
        for (int o = 1; o < HH && o * o < best; ++o) {
            int osq = o * o;
            int ylo = y - o, yhi = y + o;
            if (ylo >= 0) best = min(best, (int)t16[ylo * TPITCH + xx] + osq);
            if (yhi < HH) best = min(best, (int)t16[yhi * TPITCH + xx] + osq);
        }
        dout[sbase + (size_t)y * WW + xx] = (uint16_t)best;
    }
}

// ---------- z EDT + histogram + maxbin tracking ----------------------------
__global__ __launch_bounds__(1024)
void edt_z_hist_kernel(const uint16_t* __restrict__ d0,
                       const uint16_t* __restrict__ d1,
                       const uint16_t* __restrict__ epb,
                       const uint16_t* __restrict__ egb,
                       int* __restrict__ bigh,
                       int* __restrict__ smallh,
                       int* __restrict__ maxv)
{
    __shared__ uint16_t tile[DD * ZPITCH];
    __shared__ int lh[LBINS];
    __shared__ int blkmax;
    int tid = threadIdx.x;           // 1024
    if (tid < LBINS) lh[tid] = 0;
    if (tid == 0) blkmax = 0;

    int blk = blockIdx.x;            // dir | xt<<1 | y<<2 | b<<9
    int dir = blk & 1;
    int xt  = (blk >> 1) & 1;
    int y   = (blk >> 2) & 127;
    int b   = blk >> 9;
    const uint16_t* d = dir ? d1 : d0;
    const uint16_t* evalbits = dir ? egb : epb;  // dir0: histogram at pred edges
    size_t base = (size_t)b * NVOX + (size_t)y * WW + xt * 64;

    {   // cooperative tile load: 64 z-rows x 128B
        int z = tid >> 4, sg = tid & 15;
        uint2 v = *(const uint2*)(d + base + (size_t)z * (HH * WW) + sg * 4);
        *(uint2*)&tile[z * ZPITCH + sg * 4] = v;
    }
    __syncthreads();

    int xx = tid & 63;
    int zg = tid >> 6;               // 0..15
    int x  = xt * 64 + xx;
    int g = b * 2 + dir;
    int* gbig = bigh + (size_t)g * HBINS;
    int lane = tid & 63;

    int mymax = 0;
    #pragma unroll
    for (int k = 0; k < 4; ++k) {
        int z = zg + k * 16;
        int best = tile[z * ZPITCH + xx];
        for (int o = 1; o < DD && o * o < best; ++o) {
            int osq = o * o;
            int zlo = z - o, zhi = z + o;
            if (zlo >= 0) best = min(best, (int)tile[zlo * ZPITCH + xx] + osq);
            if (zhi < DD) best = min(best, (int)tile[zhi * ZPITCH + xx] + osq);
        }
        int v = best; if (v >= HBINS) v = HBINS - 1;
        uint32_t ew = evalbits[((b * DD + z) * HH + y) * 8 + (x >> 4)];
        bool valid = (ew >> (x & 15)) & 1;
        if (valid) mymax = max(mymax, v);
        unsigned long long active = __ballot(valid);
        while (active) {
            int leader = __ffsll(active) - 1;
            int lv = __shfl(v, leader, 64);
            unsigned long long same = __ballot(valid && (v == lv));
            if (lane == leader) {
                int cnt = __popcll(same);
                if (lv < LBINS) atomicAdd(&lh[lv], cnt);
                else            atomicAdd(&gbig[lv], cnt);
            }
            active &= ~same;
        }
    }
    // one wave-reduce of the local max, one LDS atomic per wave
    #pragma unroll
    for (int o = 1; o < 64; o <<= 1) mymax = max(mymax, __shfl_xor(mymax, o, 64));
    if (lane == 0 && mymax > 0) atomicMax(&blkmax, mymax);
    __syncthreads();
    int slot = (blk >> 1) & 7;       // spread flush over 8 targets per g
    int* dst = (slot == 0) ? gbig : (smallh + ((size_t)g * NSMALL + (slot - 1)) * LBINS);
    if (tid < LBINS) {
        int c = lh[tid];
        if (c) atomicAdd(&dst[tid], c);
    }
    if (tid == 0 && blkmax > 0) atomicMax(&maxv[g], blkmax);
}

// ---------- percentile (1 block, wave w handles g=w) -----------------------
__global__ __launch_bounds__(256)
void percentile_kernel(const int* __restrict__ bigh,
                       const int* __restrict__ smallh,
                       const int* __restrict__ maxv,
                       float* __restrict__ out)
{
    int tid = threadIdx.x;
    int gg = tid >> 6;               // wave id = g
    int lane = tid & 63;
    const int* gbig = bigh + (size_t)gg * HBINS;
    const int* gsm  = smallh + (size_t)gg * NSMALL * LBINS;
    int mb = aload(&maxv[gg]);
    if (mb >= HBINS) mb = HBINS - 1;

    // pass 1: total count n over bins [0..mb]
    int n = 0;
    for (int c0 = 0; c0 <= mb; c0 += 64) {
        int bin = c0 + lane;
        int cnt = 0;
        if (bin <= mb) {
            cnt = aload(&gbig[bin]);
            if (bin < LBINS) {
                #pragma unroll
                for (int s = 0; s < NSMALL; ++s) cnt += aload(&gsm[s * LBINS + bin]);
            }
        }
        #pragma unroll
        for (int o = 1; o < 64; o <<= 1) cnt += __shfl_xor(cnt, o, 64);
        n += cnt;
    }

    float pos = 0.95f * (float)(n - 1);
    float fpos = floorf(pos);
    int lo = (int)fpos;
    int nm1 = n - 1; if (nm1 < 0) nm1 = 0;
    if (lo < 0) lo = 0;
    if (lo > nm1) lo = nm1;
    int hi = lo + 1; if (hi > nm1) hi = nm1;
    float frac = pos - fpos;

    // pass 2: rank select
    int basec = 0, sel0 = 0, sel1 = 0;
    bool f0 = false, f1 = false;
    for (int c0 = 0; c0 <= mb && !(f0 && f1); c0 += 64) {
        int bin = c0 + lane;
        int cnt = 0;
        if (bin <= mb) {
            cnt = aload(&gbig[bin]);
            if (bin < LBINS) {
                #pragma unroll
                for (int s = 0; s < NSMALL; ++s) cnt += aload(&gsm[s * LBINS + bin]);
            }
        }
        int inc = cnt;
        #pragma unroll
        for (int o = 1; o < 64; o <<= 1) {
            int t = __shfl_up(inc, o, 64);
            if (lane >= o) inc += t;
        }
        int exc = inc - cnt;
        unsigned long long b0 = __ballot(!f0 && lo >= basec + exc && lo < basec + inc);
        if (b0) { sel0 = c0 + (__ffsll(b0) - 1); f0 = true; }
        unsigned long long b1 = __ballot(!f1 && hi >= basec + exc && hi < basec + inc);
        if (b1) { sel1 = c0 + (__ffsll(b1) - 1); f1 = true; }
        basec += __shfl(inc, 63, 64);
    }
    if (lane == 0) {
        float a = sqrtf((float)sel0);
        float bv = sqrtf((float)sel1);
        float val = a + frac * (bv - a);
        atomicMax((int*)out + (gg >> 1), __float_as_int(val));  // val>=0
    }
}

extern "C" void kernel_launch(void* const* d_in, const int* in_sizes, int n_in,
                              void* d_out, int out_size, void* d_ws, size_t ws_size,
                              hipStream_t stream)
{
    const float* pred = (const float*)d_in[0];
    const float* targ = (const float*)d_in[1];
    float* out = (float*)d_out;

    uint8_t* ws = (uint8_t*)d_ws;
    uint16_t* pb  = (uint16_t*)ws;                   // NWORDS u16
    uint16_t* tb  = pb + NWORDS;                     // NWORDS u16
    uint16_t* epb = tb + NWORDS;                     // NWORDS u16
    uint16_t* egb = epb + NWORDS;                    // NWORDS u16
    uint16_t* d0  = egb + NWORDS;                    // TOTAL u16
    uint16_t* d1  = d0 + TOTAL;                      // TOTAL u16
    int* bigh     = (int*)(d1 + TOTAL);              // 4*HBINS ints
    int* smallh   = bigh + 4 * HBINS;                // 4*NSMALL*LBINS ints
    int* maxv     = smallh + 4 * NSMALL * LBINS;     // 4 ints
    // bitpack zeroes [bigh .. bigh+ZEROINTS) = bigh||smallh||maxv

    bitpack_kernel<<<NWORDS/256, 256, 0, stream>>>(pred, targ, pb, tb, bigh);
    edt_xy_kernel<<<BB*DD*2, 1024, 0, stream>>>(pb, tb, epb, egb, d0, d1);
    edt_z_hist_kernel<<<BB*HH*2*2, 1024, 0, stream>>>(d0, d1, epb, egb,
                                                      bigh, smallh, maxv);
    percentile_kernel<<<1, 256, 0, stream>>>(bigh, smallh, maxv, out);
}

// Round 11
// 28.921 us; speedup vs baseline: 2.6109x; 1.6430x over previous
//
#include <hip/hip_runtime.h>
#include <stdint.h>

#define BB 2
#define DD 64
#define HH 128
#define WW 128
#define NVOX (DD*HH*WW)        // 2^20 per batch
#define TOTAL (BB*NVOX)        // 2097152
#define HBINS 36868            // > max finite dsq (36227)
#define NWORDS (TOTAL/16)      // 131072 uint16 mask words per volume
#define HOTN (4*8*4)           // 4 g x 8 slots x 4 hot bins
#define ZEROINTS (4*HBINS + HOTN + 4)   // bigh || hot || maxv

__device__ __forceinline__ int aload(const int* p)
{
    return __hip_atomic_load(p, __ATOMIC_RELAXED, __HIP_MEMORY_SCOPE_AGENT);
}

// ---------- bitpack: float>0.5 masks -> 16-voxel uint16 words; zero ints ---
__global__ __launch_bounds__(256)
void bitpack_kernel(const float* __restrict__ pred, const float* __restrict__ targ,
                    uint16_t* __restrict__ pb, uint16_t* __restrict__ tb,
                    int* __restrict__ zint)
{
    int gt = blockIdx.x * 256 + threadIdx.x;       // 0..NWORDS-1
    for (int t = gt; t < ZEROINTS; t += NWORDS) zint[t] = 0;

    const float4* p4 = (const float4*)pred + gt * 4;
    const float4* t4 = (const float4*)targ + gt * 4;
    uint32_t pbits = 0, tbits = 0;
    #pragma unroll
    for (int j = 0; j < 4; ++j) {
        float4 v = p4[j];
        pbits |= ((uint32_t)(v.x > 0.5f) | (uint32_t)(v.y > 0.5f) << 1 |
                  (uint32_t)(v.z > 0.5f) << 2 | (uint32_t)(v.w > 0.5f) << 3) << (4 * j);
        float4 w = t4[j];
        tbits |= ((uint32_t)(w.x > 0.5f) | (uint32_t)(w.y > 0.5f) << 1 |
                  (uint32_t)(w.z > 0.5f) << 2 | (uint32_t)(w.w > 0.5f) << 3) << (4 * j);
    }
    pb[gt] = (uint16_t)pbits;
    tb[gt] = (uint16_t)tbits;
}

// ---------- exact slow path (executed ~never; correctness fallback) --------
__device__ __forceinline__ int getbit(const uint16_t* __restrict__ M,
                                      int b, int z, int y, int x)
{
    return (M[(((size_t)(b * DD + z)) << 10) + (y << 3) + (x >> 4)] >> (x & 15)) & 1;
}

__device__ bool is_edge(const uint16_t* __restrict__ M, int b, int z, int y, int x)
{
    if (!getbit(M, b, z, y, x)) return false;
    if (x == 0 || x == WW-1 || y == 0 || y == HH-1 || z == 0 || z == DD-1) return true;
    int er = getbit(M,b,z,y,x-1) & getbit(M,b,z,y,x+1) &
             getbit(M,b,z,y-1,x) & getbit(M,b,z,y+1,x) &
             getbit(M,b,z-1,y,x) & getbit(M,b,z+1,y,x);
    return !er;
}

__device__ int slow_d2(const uint16_t* __restrict__ M, int b, int z, int y, int x)
{
    int best = 0x7FFFFFFF;
    for (int r = 2; r <= 127; ++r) {
        if (best <= r * r) break;
        for (int dz = -r; dz <= r; ++dz) {
            int zz = z + dz; if (zz < 0 || zz >= DD) continue;
            for (int dy = -r; dy <= r; ++dy) {
                int yy = y + dy; if (yy < 0 || yy >= HH) continue;
                int cheb = max(abs(dz), abs(dy));
                if (cheb == r) {
                    for (int dx = -r; dx <= r; ++dx) {
                        int xx = x + dx; if (xx < 0 || xx >= WW) continue;
                        if (is_edge(M, b, zz, yy, xx))
                            best = min(best, dz*dz + dy*dy + dx*dx);
                    }
                } else {
                    for (int t2 = 0; t2 < 2; ++t2) {
                        int dx = t2 ? r : -r;
                        int xx = x + dx; if (xx < 0 || xx >= WW) continue;
                        if (is_edge(M, b, zz, yy, xx))
                            best = min(best, dz*dz + dy*dy + dx*dx);
                    }
                }
            }
        }
    }
    return best;
}

// ---------- edges + word-parallel r<=1 distance + histogram ----------------
// One block per (slice bz, dir). E = own-surface edge word; T = other-surface
// edge words in the 3x3 (dz,dy) neighborhood (computed on the fly from mask
// bits). M0..M3 = "has T-edge at d^2 = 0/1/2/3" per voxel, via ext-row shifts.
// If an edge exists within the Chebyshev-1 cube, min d^2 over the cube is the
// global min (outside => d^2 >= 4 > 3). Residual bits -> exact slow path.
__global__ __launch_bounds__(1024)
void edge_dist_hist(const uint16_t* __restrict__ pb, const uint16_t* __restrict__ tb,
                    int* __restrict__ bigh, int* __restrict__ hot,
                    int* __restrict__ maxv)
{
    __shared__ uint16_t ownm[3][1024];   // own mask slices  z-1..z+1
    __shared__ uint16_t othm[5][1024];   // other mask slices z-2..z+2
    __shared__ uint16_t tedge[3][1024];  // other EDGE slices z-1..z+1
    __shared__ int lh[4];
    int gid = blockIdx.x, tid = threadIdx.x;
    int dir = gid & 1;
    int bz  = gid >> 1;
    int b   = bz >> 6, z = bz & (DD - 1);
    const uint16_t* own = dir ? tb : pb;   // dir0: E = pred edges
    const uint16_t* oth = dir ? pb : tb;   // dir0: distances to targ edges

    {   // cooperative load: 8 slices x 1024 words (zero out-of-range slices)
        int s = tid >> 7, off = (tid & 127) * 8;
        int zs = (s < 3) ? z + s - 1 : z + s - 5;
        const uint16_t* src = (s < 3) ? own : oth;
        uint16_t* dst = (s < 3) ? &ownm[s][off] : &othm[s - 3][off];
        if (zs >= 0 && zs < DD)
            *(uint4*)dst = *(const uint4*)(src + (((size_t)(b * DD + zs)) << 10) + off);
        else
            *(uint4*)dst = make_uint4(0, 0, 0, 0);
    }
    if (tid < 4) lh[tid] = 0;
    __syncthreads();

    int w = tid, y = w >> 3, wx = w & 7;

    // phase A: other-surface edge words for dz in {-1,0,1}
    #pragma unroll
    for (int dzi = 0; dzi < 3; ++dzi) {
        uint32_t c = othm[dzi + 1][w];
        uint32_t l = wx > 0 ? othm[dzi + 1][w - 1] : 0;
        uint32_t r = wx < 7 ? othm[dzi + 1][w + 1] : 0;
        uint32_t ext = (l >> 15) | (c << 1) | ((r & 1u) << 17);
        uint32_t m = (ext >> 1) & 0xFFFFu, L = ext & 0xFFFFu, R = (ext >> 2) & 0xFFFFu;
        uint32_t ym = y > 0   ? othm[dzi + 1][w - 8] : 0;
        uint32_t yp = y < 127 ? othm[dzi + 1][w + 8] : 0;
        uint32_t zm = othm[dzi][w], zp = othm[dzi + 2][w];
        uint32_t er = m & L & R & ym & yp & zm & zp;
        tedge[dzi][w] = (uint16_t)(m & ~er);
    }

    // E: own-surface edge word
    uint32_t E;
    {
        uint32_t c = ownm[1][w];
        uint32_t l = wx > 0 ? ownm[1][w - 1] : 0;
        uint32_t r = wx < 7 ? ownm[1][w + 1] : 0;
        uint32_t ext = (l >> 15) | (c << 1) | ((r & 1u) << 17);
        uint32_t m = (ext >> 1) & 0xFFFFu, L = ext & 0xFFFFu, R = (ext >> 2) & 0xFFFFu;
        uint32_t ym = y > 0   ? ownm[1][w - 8] : 0;
        uint32_t yp = y < 127 ? ownm[1][w + 8] : 0;
        uint32_t zm = ownm[0][w], zp = ownm[2][w];
        E = m & ~(m & L & R & ym & yp & zm & zp);
    }
    __syncthreads();   // tedge ready

    // phase B: build M0..M3 from tedge ext rows
    uint32_t M0 = 0, M1 = 0, M2 = 0, M3 = 0;
    #pragma unroll
    for (int dzi = 0; dzi < 3; ++dzi) {
        #pragma unroll
        for (int dyy = -1; dyy <= 1; ++dyy) {
            int yy = y + dyy;
            uint32_t c = 0, l = 0, r = 0;
            if (yy >= 0 && yy < HH) {
                int w2 = (yy << 3) + wx;
                c = tedge[dzi][w2];
                l = wx > 0 ? tedge[dzi][w2 - 1] : 0;
                r = wx < 7 ? tedge[dzi][w2 + 1] : 0;
            }
            uint32_t ext = (l >> 15) | (c << 1) | ((r & 1u) << 17);
            uint32_t s0 = (ext >> 1) & 0xFFFFu;                      // dx = 0
            uint32_t s1 = (ext & 0xFFFFu) | ((ext >> 2) & 0xFFFFu);  // dx = +-1
            int a = (dzi == 1 ? 0 : 1) + (dyy == 0 ? 0 : 1);
            if (a == 0)      { M0 |= s0; M1 |= s1; }
            else if (a == 1) { M1 |= s0; M2 |= s1; }
            else             { M2 |= s0; M3 |= s1; }
        }
    }

    uint32_t rem = E;
    int c0 = __popc(rem & M0); rem &= ~M0;
    int c1 = __popc(rem & M1); rem &= ~M1;
    int c2 = __popc(rem & M2); rem &= ~M2;
    int c3 = __popc(rem & M3); rem &= ~M3;

    int g = b * 2 + dir;

    // slow path for residual bits (expected ~0 voxels total)
    while (rem) {
        int i = __builtin_ctz(rem); rem &= rem - 1;
        int d2 = slow_d2(oth, b, z, y, wx * 16 + i);
        if (d2 >= HBINS) d2 = HBINS - 1;
        atomicAdd(&bigh[(size_t)g * HBINS + d2], 1);
        atomicMax(&maxv[g], d2);
    }

    // wave reduce the 4 hot counters, then one LDS add per wave
    #pragma unroll
    for (int o = 1; o < 64; o <<= 1) {
        c0 += __shfl_xor(c0, o, 64);
        c1 += __shfl_xor(c1, o, 64);
        c2 += __shfl_xor(c2, o, 64);
        c3 += __shfl_xor(c3, o, 64);
    }
    int lane = tid & 63;
    if (lane == 0) {
        if (c0) atomicAdd(&lh[0], c0);
        if (c1) atomicAdd(&lh[1], c1);
        if (c2) atomicAdd(&lh[2], c2);
        if (c3) atomicAdd(&lh[3], c3);
    }
    __syncthreads();
    if (tid < 4) {
        int v = lh[tid];
        int slot = bz & 7;             // spread global flush across 8 shadows
        if (v) atomicAdd(&hot[(g * 8 + slot) * 4 + tid], v);
    }
}

// ---------- percentile (1 block, wave w handles g=w) -----------------------
__global__ __launch_bounds__(256)
void percentile_kernel(const int* __restrict__ bigh, const int* __restrict__ hot,
                       const int* __restrict__ maxv, float* __restrict__ out)
{
    int tid = threadIdx.x;
    int gg = tid >> 6;               // wave id = g
    int lane = tid & 63;
    const int* gbig = bigh + (size_t)gg * HBINS;
    int mb = aload(&maxv[gg]);
    if (mb < 3) mb = 3;
    if (mb >= HBINS) mb = HBINS - 1;

    // pass 1: total count n over bins [0..mb]
    int n = 0;
    for (int c0 = 0; c0 <= mb; c0 += 64) {
        int bin = c0 + lane;
        int cnt = 0;
        if (bin <= mb) {
            cnt = aload(&gbig[bin]);
            if (bin < 4) {
                #pragma unroll
                for (int s = 0; s < 8; ++s) cnt += aload(&hot[(gg * 8 + s) * 4 + bin]);
            }
        }
        #pragma unroll
        for (int o = 1; o < 64; o <<= 1) cnt += __shfl_xor(cnt, o, 64);
        n += cnt;
    }

    float pos = 0.95f * (float)(n - 1);
    float fpos = floorf(pos);
    int lo = (int)fpos;
    int nm1 = n - 1; if (nm1 < 0) nm1 = 0;
    if (lo < 0) lo = 0;
    if (lo > nm1) lo = nm1;
    int hi = lo + 1; if (hi > nm1) hi = nm1;
    float frac = pos - fpos;

    // pass 2: rank select
    int basec = 0, sel0 = 0, sel1 = 0;
    bool f0 = false, f1 = false;
    for (int c0 = 0; c0 <= mb && !(f0 && f1); c0 += 64) {
        int bin = c0 + lane;
        int cnt = 0;
        if (bin <= mb) {
            cnt = aload(&gbig[bin]);
            if (bin < 4) {
                #pragma unroll
                for (int s = 0; s < 8; ++s) cnt += aload(&hot[(gg * 8 + s) * 4 + bin]);
            }
        }
        int inc = cnt;
        #pragma unroll
        for (int o = 1; o < 64; o <<= 1) {
            int t = __shfl_up(inc, o, 64);
            if (lane >= o) inc += t;
        }
        int exc = inc - cnt;
        unsigned long long b0 = __ballot(!f0 && lo >= basec + exc && lo < basec + inc);
        if (b0) { sel0 = c0 + (__ffsll(b0) - 1); f0 = true; }
        unsigned long long b1 = __ballot(!f1 && hi >= basec + exc && hi < basec + inc);
        if (b1) { sel1 = c0 + (__ffsll(b1) - 1); f1 = true; }
        basec += __shfl(inc, 63, 64);
    }
    if (lane == 0) {
        float a = sqrtf((float)sel0);
        float bv = sqrtf((float)sel1);
        float val = a + frac * (bv - a);
        atomicMax((int*)out + (gg >> 1), __float_as_int(val));  // val>=0
    }
}

extern "C" void kernel_launch(void* const* d_in, const int* in_sizes, int n_in,
                              void* d_out, int out_size, void* d_ws, size_t ws_size,
                              hipStream_t stream)
{
    const float* pred = (const float*)d_in[0];
    const float* targ = (const float*)d_in[1];
    float* out = (float*)d_out;

    uint8_t* ws = (uint8_t*)d_ws;
    uint16_t* pb = (uint16_t*)ws;                    // NWORDS u16 (pred mask bits)
    uint16_t* tb = pb + NWORDS;                      // NWORDS u16 (targ mask bits)
    int* bigh    = (int*)(tb + NWORDS);              // 4*HBINS ints (slow path)
    int* hot     = bigh + 4 * HBINS;                 // HOTN ints (d^2 = 0..3)
    int* maxv    = hot + HOTN;                       // 4 ints
    // bitpack zeroes [bigh .. bigh+ZEROINTS) = bigh||hot||maxv

    bitpack_kernel<<<NWORDS/256, 256, 0, stream>>>(pred, targ, pb, tb, bigh);
    edge_dist_hist<<<BB*DD*2, 1024, 0, stream>>>(pb, tb, bigh, hot, maxv);
    percentile_kernel<<<1, 256, 0, stream>>>(bigh, hot, maxv, out);
}

// Round 12
// 27.812 us; speedup vs baseline: 2.7151x; 1.0399x over previous
//
#include <hip/hip_runtime.h>
#include <stdint.h>

#define BB 2
#define DD 64
#define HH 128
#define WW 128
#define NVOX (DD*HH*WW)        // 2^20 per batch
#define TOTAL (BB*NVOX)        // 2097152
#define HBINS 36868            // > max finite dsq (36227)
#define NWORDS (TOTAL/16)      // 131072 uint16 mask words per volume
#define HOTN (4*8*4)           // 4 g x 8 slots x 4 hot bins
#define ZEROINTS (4*HBINS + HOTN + 4 + 1)   // bigh || hot || maxv || done
#define EGRID (BB*DD*2)        // 256 blocks

__device__ __forceinline__ int aload(const int* p)
{
    return __hip_atomic_load(p, __ATOMIC_RELAXED, __HIP_MEMORY_SCOPE_AGENT);
}

// ---------- bitpack: float>0.5 masks -> 16-voxel uint16 words; zero ints ---
__global__ __launch_bounds__(256)
void bitpack_kernel(const float* __restrict__ pred, const float* __restrict__ targ,
                    uint16_t* __restrict__ pb, uint16_t* __restrict__ tb,
                    int* __restrict__ zint)
{
    int gt = blockIdx.x * 256 + threadIdx.x;       // 0..NWORDS-1
    for (int t = gt; t < ZEROINTS; t += NWORDS) zint[t] = 0;

    const float4* p4 = (const float4*)pred + gt * 4;
    const float4* t4 = (const float4*)targ + gt * 4;
    uint32_t pbits = 0, tbits = 0;
    #pragma unroll
    for (int j = 0; j < 4; ++j) {
        float4 v = p4[j];
        pbits |= ((uint32_t)(v.x > 0.5f) | (uint32_t)(v.y > 0.5f) << 1 |
                  (uint32_t)(v.z > 0.5f) << 2 | (uint32_t)(v.w > 0.5f) << 3) << (4 * j);
        float4 w = t4[j];
        tbits |= ((uint32_t)(w.x > 0.5f) | (uint32_t)(w.y > 0.5f) << 1 |
                  (uint32_t)(w.z > 0.5f) << 2 | (uint32_t)(w.w > 0.5f) << 3) << (4 * j);
    }
    pb[gt] = (uint16_t)pbits;
    tb[gt] = (uint16_t)tbits;
}

// ---------- exact slow path (executed ~never; correctness fallback) --------
__device__ __forceinline__ int getbit(const uint16_t* __restrict__ M,
                                      int b, int z, int y, int x)
{
    return (M[(((size_t)(b * DD + z)) << 10) + (y << 3) + (x >> 4)] >> (x & 15)) & 1;
}

__device__ bool is_edge(const uint16_t* __restrict__ M, int b, int z, int y, int x)
{
    if (!getbit(M, b, z, y, x)) return false;
    if (x == 0 || x == WW-1 || y == 0 || y == HH-1 || z == 0 || z == DD-1) return true;
    int er = getbit(M,b,z,y,x-1) & getbit(M,b,z,y,x+1) &
             getbit(M,b,z,y-1,x) & getbit(M,b,z,y+1,x) &
             getbit(M,b,z-1,y,x) & getbit(M,b,z+1,y,x);
    return !er;
}

__device__ int slow_d2(const uint16_t* __restrict__ M, int b, int z, int y, int x)
{
    int best = 0x7FFFFFFF;
    for (int r = 2; r <= 127; ++r) {
        if (best <= r * r) break;
        for (int dz = -r; dz <= r; ++dz) {
            int zz = z + dz; if (zz < 0 || zz >= DD) continue;
            for (int dy = -r; dy <= r; ++dy) {
                int yy = y + dy; if (yy < 0 || yy >= HH) continue;
                int cheb = max(abs(dz), abs(dy));
                if (cheb == r) {
                    for (int dx = -r; dx <= r; ++dx) {
                        int xx = x + dx; if (xx < 0 || xx >= WW) continue;
                        if (is_edge(M, b, zz, yy, xx))
                            best = min(best, dz*dz + dy*dy + dx*dx);
                    }
                } else {
                    for (int t2 = 0; t2 < 2; ++t2) {
                        int dx = t2 ? r : -r;
                        int xx = x + dx; if (xx < 0 || xx >= WW) continue;
                        if (is_edge(M, b, zz, yy, xx))
                            best = min(best, dz*dz + dy*dy + dx*dx);
                    }
                }
            }
        }
    }
    return best;
}

// ---------- edges + word-parallel r<=1 distance + histogram + tail ---------
__global__ __launch_bounds__(1024)
void edge_dist_hist(const uint16_t* __restrict__ pb, const uint16_t* __restrict__ tb,
                    int* __restrict__ bigh, int* __restrict__ hot,
                    int* __restrict__ maxv, int* __restrict__ done,
                    float* __restrict__ out)
{
    __shared__ uint16_t ownm[3][1024];   // own mask slices  z-1..z+1
    __shared__ uint16_t othm[5][1024];   // other mask slices z-2..z+2
    __shared__ uint16_t tedge[3][1024];  // other EDGE slices z-1..z+1
    __shared__ int lh[4];
    __shared__ int lastflag;
    int gid = blockIdx.x, tid = threadIdx.x;
    int dir = gid & 1;
    int bz  = gid >> 1;
    int b   = bz >> 6, z = bz & (DD - 1);
    const uint16_t* own = dir ? tb : pb;   // dir0: E = pred edges
    const uint16_t* oth = dir ? pb : tb;   // dir0: distances to targ edges

    {   // cooperative load: 8 slices x 1024 words (zero out-of-range slices)
        int s = tid >> 7, off = (tid & 127) * 8;
        int zs = (s < 3) ? z + s - 1 : z + s - 5;
        const uint16_t* src = (s < 3) ? own : oth;
        uint16_t* dst = (s < 3) ? &ownm[s][off] : &othm[s - 3][off];
        if (zs >= 0 && zs < DD)
            *(uint4*)dst = *(const uint4*)(src + (((size_t)(b * DD + zs)) << 10) + off);
        else
            *(uint4*)dst = make_uint4(0, 0, 0, 0);
    }
    if (tid < 4) lh[tid] = 0;
    __syncthreads();

    int w = tid, y = w >> 3, wx = w & 7;

    // phase A: other-surface edge words for dz in {-1,0,1}
    #pragma unroll
    for (int dzi = 0; dzi < 3; ++dzi) {
        uint32_t c = othm[dzi + 1][w];
        uint32_t l = wx > 0 ? othm[dzi + 1][w - 1] : 0;
        uint32_t r = wx < 7 ? othm[dzi + 1][w + 1] : 0;
        uint32_t ext = (l >> 15) | (c << 1) | ((r & 1u) << 17);
        uint32_t m = (ext >> 1) & 0xFFFFu, L = ext & 0xFFFFu, R = (ext >> 2) & 0xFFFFu;
        uint32_t ym = y > 0   ? othm[dzi + 1][w - 8] : 0;
        uint32_t yp = y < 127 ? othm[dzi + 1][w + 8] : 0;
        uint32_t zm = othm[dzi][w], zp = othm[dzi + 2][w];
        uint32_t er = m & L & R & ym & yp & zm & zp;
        tedge[dzi][w] = (uint16_t)(m & ~er);
    }

    // E: own-surface edge word
    uint32_t E;
    {
        uint32_t c = ownm[1][w];
        uint32_t l = wx > 0 ? ownm[1][w - 1] : 0;
        uint32_t r = wx < 7 ? ownm[1][w + 1] : 0;
        uint32_t ext = (l >> 15) | (c << 1) | ((r & 1u) << 17);
        uint32_t m = (ext >> 1) & 0xFFFFu, L = ext & 0xFFFFu, R = (ext >> 2) & 0xFFFFu;
        uint32_t ym = y > 0   ? ownm[1][w - 8] : 0;
        uint32_t yp = y < 127 ? ownm[1][w + 8] : 0;
        uint32_t zm = ownm[0][w], zp = ownm[2][w];
        E = m & ~(m & L & R & ym & yp & zm & zp);
    }
    __syncthreads();   // tedge ready

    // phase B: build M0..M3 (has oth-edge at d^2=0/1/2/3) from tedge ext rows
    uint32_t M0 = 0, M1 = 0, M2 = 0, M3 = 0;
    #pragma unroll
    for (int dzi = 0; dzi < 3; ++dzi) {
        #pragma unroll
        for (int dyy = -1; dyy <= 1; ++dyy) {
            int yy = y + dyy;
            uint32_t c = 0, l = 0, r = 0;
            if (yy >= 0 && yy < HH) {
                int w2 = (yy << 3) + wx;
                c = tedge[dzi][w2];
                l = wx > 0 ? tedge[dzi][w2 - 1] : 0;
                r = wx < 7 ? tedge[dzi][w2 + 1] : 0;
            }
            uint32_t ext = (l >> 15) | (c << 1) | ((r & 1u) << 17);
            uint32_t s0 = (ext >> 1) & 0xFFFFu;                      // dx = 0
            uint32_t s1 = (ext & 0xFFFFu) | ((ext >> 2) & 0xFFFFu);  // dx = +-1
            int a = (dzi == 1 ? 0 : 1) + (dyy == 0 ? 0 : 1);
            if (a == 0)      { M0 |= s0; M1 |= s1; }
            else if (a == 1) { M1 |= s0; M2 |= s1; }
            else             { M2 |= s0; M3 |= s1; }
        }
    }

    uint32_t rem = E;
    int c0 = __popc(rem & M0); rem &= ~M0;
    int c1 = __popc(rem & M1); rem &= ~M1;
    int c2 = __popc(rem & M2); rem &= ~M2;
    int c3 = __popc(rem & M3); rem &= ~M3;

    int g = b * 2 + dir;

    // slow path for residual bits (expected ~0 voxels total)
    while (rem) {
        int i = __builtin_ctz(rem); rem &= rem - 1;
        int d2 = slow_d2(oth, b, z, y, wx * 16 + i);
        if (d2 >= HBINS) d2 = HBINS - 1;
        atomicAdd(&bigh[(size_t)g * HBINS + d2], 1);
        atomicMax(&maxv[g], d2);
    }

    // wave reduce the 4 hot counters, then one LDS add per wave
    #pragma unroll
    for (int o = 1; o < 64; o <<= 1) {
        c0 += __shfl_xor(c0, o, 64);
        c1 += __shfl_xor(c1, o, 64);
        c2 += __shfl_xor(c2, o, 64);
        c3 += __shfl_xor(c3, o, 64);
    }
    int lane = tid & 63;
    if (lane == 0) {
        if (c0) atomicAdd(&lh[0], c0);
        if (c1) atomicAdd(&lh[1], c1);
        if (c2) atomicAdd(&lh[2], c2);
        if (c3) atomicAdd(&lh[3], c3);
    }
    __syncthreads();
    if (tid < 4) {
        int v = lh[tid];
        int slot = bz & 7;             // spread global flush across 8 shadows
        if (v) atomicAdd(&hot[(g * 8 + slot) * 4 + tid], v);
    }
    // drain this block's flush atomics (syncthreads implies vmcnt(0) per wave)
    __syncthreads();
    if (tid == 0) {
        int old = __hip_atomic_fetch_add(done, 1, __ATOMIC_RELAXED,
                                         __HIP_MEMORY_SCOPE_AGENT);
        lastflag = (old == EGRID - 1);
    }
    __syncthreads();
    if (!lastflag) return;

    // ------------- last block only: percentile (wave w handles g=w) -------
    if (tid >= 256) return;
    {
        int gg = tid >> 6;
        const int* gbig = bigh + (size_t)gg * HBINS;
        int mb = aload(&maxv[gg]);
        if (mb < 3) mb = 3;
        if (mb >= HBINS) mb = HBINS - 1;

        // pass 1: total count n over bins [0..mb]
        int n = 0;
        for (int cc = 0; cc <= mb; cc += 64) {
            int bin = cc + lane;
            int cnt = 0;
            if (bin <= mb) {
                cnt = aload(&gbig[bin]);
                if (bin < 4) {
                    #pragma unroll
                    for (int s = 0; s < 8; ++s) cnt += aload(&hot[(gg * 8 + s) * 4 + bin]);
                }
            }
            #pragma unroll
            for (int o = 1; o < 64; o <<= 1) cnt += __shfl_xor(cnt, o, 64);
            n += cnt;
        }

        float pos = 0.95f * (float)(n - 1);
        float fpos = floorf(pos);
        int lo = (int)fpos;
        int nm1 = n - 1; if (nm1 < 0) nm1 = 0;
        if (lo < 0) lo = 0;
        if (lo > nm1) lo = nm1;
        int hi = lo + 1; if (hi > nm1) hi = nm1;
        float frac = pos - fpos;

        // pass 2: rank select
        int basec = 0, sel0 = 0, sel1 = 0;
        bool f0 = false, f1 = false;
        for (int cc = 0; cc <= mb && !(f0 && f1); cc += 64) {
            int bin = cc + lane;
            int cnt = 0;
            if (bin <= mb) {
                cnt = aload(&gbig[bin]);
                if (bin < 4) {
                    #pragma unroll
                    for (int s = 0; s < 8; ++s) cnt += aload(&hot[(gg * 8 + s) * 4 + bin]);
                }
            }
            int inc = cnt;
            #pragma unroll
            for (int o = 1; o < 64; o <<= 1) {
                int t = __shfl_up(inc, o, 64);
                if (lane >= o) inc += t;
            }
            int exc = inc - cnt;
            unsigned long long b0 = __ballot(!f0 && lo >= basec + exc && lo < basec + inc);
            if (b0) { sel0 = cc + (__ffsll(b0) - 1); f0 = true; }
            unsigned long long b1 = __ballot(!f1 && hi >= basec + exc && hi < basec + inc);
            if (b1) { sel1 = cc + (__ffsll(b1) - 1); f1 = true; }
            basec += __shfl(inc, 63, 64);
        }
        if (lane == 0) {
            float a = sqrtf((float)sel0);
            float bv = sqrtf((float)sel1);
            float val = a + frac * (bv - a);
            atomicMax((int*)out + (gg >> 1), __float_as_int(val));  // val>=0
        }
    }
}

extern "C" void kernel_launch(void* const* d_in, const int* in_sizes, int n_in,
                              void* d_out, int out_size, void* d_ws, size_t ws_size,
                              hipStream_t stream)
{
    const float* pred = (const float*)d_in[0];
    const float* targ = (const float*)d_in[1];
    float* out = (float*)d_out;

    uint8_t* ws = (uint8_t*)d_ws;
    uint16_t* pb = (uint16_t*)ws;                    // NWORDS u16 (pred mask bits)
    uint16_t* tb = pb + NWORDS;                      // NWORDS u16 (targ mask bits)
    int* bigh    = (int*)(tb + NWORDS);              // 4*HBINS ints (slow path)
    int* hot     = bigh + 4 * HBINS;                 // HOTN ints (d^2 = 0..3)
    int* maxv    = hot + HOTN;                       // 4 ints
    int* done    = maxv + 4;                         // 1 int
    // bitpack zeroes [bigh .. bigh+ZEROINTS) = bigh||hot||maxv||done

    bitpack_kernel<<<NWORDS/256, 256, 0, stream>>>(pred, targ, pb, tb, bigh);
    edge_dist_hist<<<EGRID, 1024, 0, stream>>>(pb, tb, bigh, hot, maxv, done, out);
}